// Round 12
// baseline (185.712 us; speedup 1.0000x reference)
//
#include <hip/hip_runtime.h>
#include <math.h>

// MVAE forward, round 12: 7-WG expert-decomposed persistent kernel.
// Topology: WG 0..5 = expert e; WG 6 = gate. Each WG computes the encoder
// redundantly (z in LDS), then its own chain ENTIRELY WG-locally -> only ONE
// grid barrier (before the final decode). Layers processed in 64-row chunks:
// weights staged global->LDS via global_load_lds (the proven un-sinkable
// primitive; plain loads get compiler-serialized — r3/r11 lesson) into a
// double-buffered 2x72KB LDS buffer, pipelined with plain __syncthreads only
// (stage c+1 issued before compute c; block-ending sync drains it).
// Compute = r5-proven wred row dots. Cross-WG: g_oute via cstore/cload +
// r5-form gridbar (NWG=7).

#define NWG   7
#define BLOCK 256

__device__ __align__(128) float g_oute[384];

struct P {
  const float *prev, *curr, *eps;
  const float *ew0,*eb0,*ew1,*eb1,*ew2,*eb2;
  const float *muw,*mub,*lvw,*lvb;
  const float *gw0,*gb0,*gw1,*gb1,*gw2,*gb2,*gw3,*gb3;
  const float *xw0,*xb0,*xw1,*xb1,*xw2,*xb2,*xw3,*xb3;
  float* out;
};

__device__ __forceinline__ float cload(const float* a) {
  int v = __hip_atomic_load((const int*)a, __ATOMIC_RELAXED,
                            __HIP_MEMORY_SCOPE_AGENT);
  return __int_as_float(v);
}
__device__ __forceinline__ void cstore(float* a, float v) {
  __hip_atomic_store((int*)a, __float_as_int(v), __ATOMIC_RELAXED,
                     __HIP_MEMORY_SCOPE_AGENT);
}
__device__ __forceinline__ void gll16(const void* g, void* l) {
  __builtin_amdgcn_global_load_lds((const __attribute__((address_space(1))) void*)g,
                                   (__attribute__((address_space(3))) void*)l,
                                   16, 0, 0);
}
__device__ __forceinline__ void gll4(const void* g, void* l) {
  __builtin_amdgcn_global_load_lds((const __attribute__((address_space(1))) void*)g,
                                   (__attribute__((address_space(3))) void*)l,
                                   4, 0, 0);
}
__device__ __forceinline__ float wred(float v) {
#pragma unroll
  for (int m = 32; m; m >>= 1) v += __shfl_xor(v, m, 64);
  return v;
}
__device__ __forceinline__ float elu(float x) { return x > 0.f ? x : expm1f(x); }
__device__ __forceinline__ float dot4(float4 a, float4 b) {
  return a.x*b.x + a.y*b.y + a.z*b.z + a.w*b.w;
}

// ---- chunk helpers ----
__device__ __forceinline__ int rows_of(int c, int nper, int tot, int wvin, int* base) {
  int b0 = c * 4 * nper + wvin * nper;
  *base = b0;
  int n = tot - b0; if (n < 0) n = 0; if (n > nper) n = nper;
  return n;
}

// stage n rows (rowlen in {94,124,256,288}); LDS stride: 94->96, else rowlen.
__device__ __forceinline__ void stage_rows(const float* W, int rowlen, int stride,
                                           int row0, int n, float* wavebuf, int lane) {
  for (int i = 0; i < n; ++i) {
    const float* src = W + (size_t)(row0 + i) * rowlen;
    float* dst = wavebuf + i * stride;
    if (rowlen == 256) {
      gll16(src + lane * 4, dst);
    } else if (rowlen == 288) {
      gll16(src + lane * 4, dst);
      if (lane < 8) gll16(src + 256 + lane * 4, dst + 256);
    } else if (rowlen == 124) {
      if (lane < 31) gll16(src + lane * 4, dst);
    } else {  // 94 floats, stride 96 (r5 pattern)
      if (lane < 23)       gll16(src + lane * 4, dst);
      else if (lane == 23) { gll4(src + 92, dst + 69);   // -> float 92
                             gll4(src + 93, dst + 70); } // -> float 93
    }
  }
}

// ---- row dot variants (r5-proven shapes) ----
__device__ __forceinline__ float rowdot256(const float* wrow, float4 x, int lane) {
  float4 w = *(const float4*)(wrow + 4 * lane);
  return wred(dot4(w, x));
}
__device__ __forceinline__ float rowdot124(const float* wrow, float4 x, int lane) {
  float4 w = make_float4(0.f, 0.f, 0.f, 0.f);
  if (lane < 31) w = *(const float4*)(wrow + 4 * lane);
  return wred(dot4(w, x));
}
__device__ __forceinline__ float rowdot94(const float* wrow, const float* zp, int lane) {
  float xa = zp[lane];
  float xb = (lane < 30) ? zp[64 + lane] : 0.f;
  float wa = wrow[lane];
  float wb = (lane < 30) ? wrow[64 + lane] : 0.f;
  return wred(wa * xa + wb * xb);
}
__device__ __forceinline__ float rowdot288(const float* wrow, const float* zp,
                                           const float* h, int lane) {
  float4 w = *(const float4*)(wrow + 4 * lane);
  float4 xh;
  if (lane < 8) xh = *(const float4*)(zp + 4 * lane);
  else          xh = *(const float4*)(h + 4 * lane - 32);
  float s = dot4(w, xh);
  if (lane < 32) s += wrow[256 + lane] * h[224 + lane];
  return wred(s);
}

// ---- pipelined layer drivers (double-buffered, plain __syncthreads) ----
// KIND: 0=124(x in s_x), 1=256(x=xin vec), 2=94([z|prev]), 3=288([z|hprev])
template<int KIND>
__device__ __forceinline__ void run_layer(const float* W, const float* bias,
    const float* xin, const float* hprev, float* out, float* gout,
    int tot, bool doelu, float* wb0, float* wb1, int wvin, int lane) {
  const int rowlen = (KIND == 0) ? 124 : (KIND == 1) ? 256 : (KIND == 2) ? 94 : 288;
  const int stride = (KIND == 2) ? 96 : rowlen;
  const int nper   = (KIND == 0 || KIND == 2) ? 32 : 16;
  const int nchunk = (tot + 4 * nper - 1) / (4 * nper);

  { int b0; int n = rows_of(0, nper, tot, wvin, &b0);
    stage_rows(W, rowlen, stride, b0, n, wb0, lane); }
  __syncthreads();
  for (int c = 0; c < nchunk; ++c) {
    float* cur = (c & 1) ? wb1 : wb0;
    float* nxt = (c & 1) ? wb0 : wb1;
    if (c + 1 < nchunk) {
      int b0; int n = rows_of(c + 1, nper, tot, wvin, &b0);
      stage_rows(W, rowlen, stride, b0, n, nxt, lane);
    }
    int b0; int n = rows_of(c, nper, tot, wvin, &b0);
    float4 x = make_float4(0.f, 0.f, 0.f, 0.f);
    if (KIND == 1) x = *(const float4*)(xin + 4 * lane);
    if (KIND == 0 && lane < 31) x = *(const float4*)(xin + 4 * lane);
    for (int i = 0; i < n; ++i) {
      const float* wrow = cur + i * stride;
      float s;
      if      (KIND == 0) s = rowdot124(wrow, x, lane);
      else if (KIND == 1) s = rowdot256(wrow, x, lane);
      else if (KIND == 2) s = rowdot94(wrow, xin, lane);
      else                s = rowdot288(wrow, xin, hprev, lane);
      if (!lane) {
        float v = s + bias[b0 + i];
        if (gout) cstore(&gout[b0 + i], v);            // out_e path (no elu)
        else      out[b0 + i] = doelu ? elu(v) : v;
      }
    }
    __syncthreads();
  }
}

__global__ __launch_bounds__(BLOCK, 1) void mvae_main(P p, int* flags) {
  const int tid  = threadIdx.x;
  const int lane = tid & 63;
  const int wvin = tid >> 6;
  const int b    = blockIdx.x;          // 0..5 experts, 6 gate

  __shared__ __align__(16) float s_wbuf[2][4][16 * 288];   // 2 x 72KB
  __shared__ __align__(16) float s_act[2][256];
  __shared__ __align__(16) float s_x[128];    // [prev|curr] (124)
  __shared__ __align__(16) float s_zp[96];    // [z(32) | prev(62)]
  __shared__ float s_ml[64];
  __shared__ float s_gates[8];

  float* wb0 = &s_wbuf[0][wvin][0];
  float* wb1 = &s_wbuf[1][wvin][0];

  // entry: tiny inputs into LDS
  if (tid < 124) s_x[tid] = (tid < 62) ? p.prev[tid] : p.curr[tid - 62];
  if (tid < 62)  s_zp[32 + tid] = p.prev[tid];
  float epsv = (tid < 32) ? p.eps[tid] : 0.f;

  // ===== redundant encoder (every WG) =====
  run_layer<0>(p.ew0, p.eb0, s_x,      nullptr, s_act[0], nullptr, 256, true, wb0, wb1, wvin, lane);
  run_layer<1>(p.ew1, p.eb1, s_act[0], nullptr, s_act[1], nullptr, 256, true, wb0, wb1, wvin, lane);
  run_layer<1>(p.ew2, p.eb2, s_act[1], nullptr, s_act[0], nullptr, 256, true, wb0, wb1, wvin, lane);

  // mu/lv: one 64-row chunk, per-row src select
  {
    for (int i = 0; i < 16; ++i) {
      int g = wvin * 16 + i;
      const float* src = (g < 32) ? p.muw + g * 256 : p.lvw + (g - 32) * 256;
      gll16(src + lane * 4, wb0 + i * 256);
    }
    __syncthreads();
    float4 x = *(const float4*)(s_act[0] + 4 * lane);
    for (int i = 0; i < 16; ++i) {
      int g = wvin * 16 + i;
      float s = rowdot256(wb0 + i * 256, x, lane);
      if (!lane) s_ml[g] = s + ((g < 32) ? p.mub[g] : p.lvb[g - 32]);
    }
    __syncthreads();
  }
  // z (gate WG also emits mu/logvar outputs)
  if (tid < 32) {
    float mu = s_ml[tid], lv = s_ml[32 + tid];
    s_zp[tid] = mu + epsv * expf(0.5f * lv);
    if (b == 6) { p.out[62 + tid] = mu; p.out[94 + tid] = lv; }
  }
  __syncthreads();

  if (b < 6) {
    // ===== expert chain, fully WG-local =====
    run_layer<2>(p.xw0 + (size_t)b * 256 * 94,  p.xb0 + b * 256, s_zp, nullptr,
                 s_act[1], nullptr, 256, true, wb0, wb1, wvin, lane);
    run_layer<3>(p.xw1 + (size_t)b * 256 * 288, p.xb1 + b * 256, s_zp, s_act[1],
                 s_act[0], nullptr, 256, true, wb0, wb1, wvin, lane);
    run_layer<3>(p.xw2 + (size_t)b * 256 * 288, p.xb2 + b * 256, s_zp, s_act[0],
                 s_act[1], nullptr, 256, true, wb0, wb1, wvin, lane);
    run_layer<3>(p.xw3 + (size_t)b * 62 * 288,  p.xb3 + b * 62,  s_zp, s_act[1],
                 nullptr, g_oute + b * 62, 62, false, wb0, wb1, wvin, lane);
    // arrive (drains cstores) and exit
    __syncthreads();
    if (tid == 0)
      __hip_atomic_store(&flags[b * 16], 1, __ATOMIC_RELAXED,
                         __HIP_MEMORY_SCOPE_AGENT);
    return;
  }

  // ===== gate chain (WG 6) =====
  run_layer<2>(p.gw0, p.gb0, s_zp,     nullptr, s_act[1], nullptr, 256, true, wb0, wb1, wvin, lane);
  run_layer<1>(p.gw1, p.gb1, s_act[1], nullptr, s_act[0], nullptr, 256, true, wb0, wb1, wvin, lane);
  run_layer<1>(p.gw2, p.gb2, s_act[0], nullptr, s_act[1], nullptr, 256, true, wb0, wb1, wvin, lane);
  run_layer<1>(p.gw3, p.gb3, s_act[1], nullptr, s_gates,  nullptr, 6,   false, wb0, wb1, wvin, lane);

  // barrier: arrive + wait for all 7 WGs
  __syncthreads();
  if (tid == 0)
    __hip_atomic_store(&flags[6 * 16], 1, __ATOMIC_RELAXED,
                       __HIP_MEMORY_SCOPE_AGENT);
  if (tid < NWG) {
    while (__hip_atomic_load(&flags[tid * 16],
                             __ATOMIC_RELAXED, __HIP_MEMORY_SCOPE_AGENT) < 1)
      __builtin_amdgcn_s_sleep(1);
  }
  __syncthreads();

  // decode: out[o] = sum_e gates[e] * oute[e][o]
  {
    float* s_o = &s_wbuf[0][0][0];     // reuse staged-weights LDS
    s_o[tid] = cload(&g_oute[tid]);
    if (tid < 116) s_o[256 + tid] = cload(&g_oute[256 + tid]);
    __syncthreads();
    if (tid < 62) {
      float s = 0.f;
#pragma unroll
      for (int e = 0; e < 6; ++e) s += s_gates[e] * s_o[e * 62 + tid];
      p.out[tid] = s;
    }
  }
}

extern "C" void kernel_launch(void* const* d_in, const int* in_sizes, int n_in,
                              void* d_out, int out_size, void* d_ws, size_t ws_size,
                              hipStream_t stream) {
  (void)in_sizes; (void)n_in; (void)out_size; (void)ws_size;
  const float* const* in = (const float* const*)d_in;
  P p;
  p.prev = in[0];  p.curr = in[1];  p.eps = in[2];
  p.ew0 = in[3];   p.eb0 = in[4];   p.ew1 = in[5];  p.eb1 = in[6];
  p.ew2 = in[7];   p.eb2 = in[8];
  p.muw = in[9];   p.mub = in[10];  p.lvw = in[11]; p.lvb = in[12];
  p.gw0 = in[13];  p.gb0 = in[14];  p.gw1 = in[15]; p.gb1 = in[16];
  p.gw2 = in[17];  p.gb2 = in[18];  p.gw3 = in[19]; p.gb3 = in[20];
  p.xw0 = in[21];  p.xb0 = in[22];  p.xw1 = in[23]; p.xb1 = in[24];
  p.xw2 = in[25];  p.xb2 = in[26];  p.xw3 = in[27]; p.xb3 = in[28];
  p.out = (float*)d_out;

  int* flags = (int*)d_ws;                        // 7 WGs x 1 cacheline
  hipMemsetAsync(flags, 0, NWG * 16 * sizeof(int), stream);
  mvae_main<<<NWG, BLOCK, 0, stream>>>(p, flags);
}

// Round 13
// 35.274 us; speedup vs baseline: 5.2648x; 5.2648x over previous
//
#include <hip/hip_runtime.h>
#include <math.h>

// MVAE forward, round 13: full-width row-per-wave persistent kernel.
// 256 WGs x 4 waves = 1024 waves; each stage assigns <=2 rows per wave, so a
// stage costs ~1 coalesced weight-load round trip + wred + sc1 store. NO LDS
// weight staging, NO gll16 bulk streams (r5/r12 showed that family has a
// ~35us floor). Weights are read once, coalesced, by their owning wave.
// Cross-WG data: cstore/cload (sc1, MALL-coherent) — r3's proven discipline.
// Barrier: r5-form per-WG flag + wave-0 poll (4 flags/lane), 8 barriers.

#define NWG   256
#define BLOCK 256

__device__ __align__(128) float g_a0[256];
__device__ __align__(128) float g_a1[256];
__device__ __align__(128) float g_a2[256];
__device__ __align__(128) float g_mu[32];
__device__ __align__(128) float g_lv[32];
__device__ __align__(128) float g_g0[256];
__device__ __align__(128) float g_g1[256];
__device__ __align__(128) float g_g2[256];
__device__ __align__(128) float g_gates[32];
__device__ __align__(128) float g_h0[1536];
__device__ __align__(128) float g_h1[1536];
__device__ __align__(128) float g_h2[1536];
__device__ __align__(128) float g_oute[384];

struct P {
  const float *prev, *curr, *eps;
  const float *ew0,*eb0,*ew1,*eb1,*ew2,*eb2;
  const float *muw,*mub,*lvw,*lvb;
  const float *gw0,*gb0,*gw1,*gb1,*gw2,*gb2,*gw3,*gb3;
  const float *xw0,*xb0,*xw1,*xb1,*xw2,*xb2,*xw3,*xb3;
  float* out;
};

__device__ __forceinline__ float cload(const float* a) {
  int v = __hip_atomic_load((const int*)a, __ATOMIC_RELAXED,
                            __HIP_MEMORY_SCOPE_AGENT);
  return __int_as_float(v);
}
__device__ __forceinline__ void cstore(float* a, float v) {
  __hip_atomic_store((int*)a, __float_as_int(v), __ATOMIC_RELAXED,
                     __HIP_MEMORY_SCOPE_AGENT);
}
__device__ __forceinline__ float4 cload4(const float* a) {
  float4 r;
  r.x = cload(a + 0); r.y = cload(a + 1);
  r.z = cload(a + 2); r.w = cload(a + 3);
  return r;
}
__device__ __forceinline__ float wred(float v) {
#pragma unroll
  for (int m = 32; m; m >>= 1) v += __shfl_xor(v, m, 64);
  return v;
}
__device__ __forceinline__ float elu(float x) { return x > 0.f ? x : expm1f(x); }
__device__ __forceinline__ float dot4(float4 a, float4 b) {
  return a.x*b.x + a.y*b.y + a.z*b.z + a.w*b.w;
}

// grid barrier, 256 WGs: per-WG flag cacheline; 64 lanes x 4 flags parallel poll
__device__ __forceinline__ void gridbar(int* flags, int phase) {
  __syncthreads();                 // vmcnt(0) drain: sc1 stores ack'd at MALL
  if (threadIdx.x == 0)
    __hip_atomic_store(&flags[blockIdx.x * 16], phase,
                       __ATOMIC_RELAXED, __HIP_MEMORY_SCOPE_AGENT);
  if (threadIdx.x < 64) {
    const int l = threadIdx.x;
    for (;;) {
      int v0 = __hip_atomic_load(&flags[(l)       * 16], __ATOMIC_RELAXED, __HIP_MEMORY_SCOPE_AGENT);
      int v1 = __hip_atomic_load(&flags[(l +  64) * 16], __ATOMIC_RELAXED, __HIP_MEMORY_SCOPE_AGENT);
      int v2 = __hip_atomic_load(&flags[(l + 128) * 16], __ATOMIC_RELAXED, __HIP_MEMORY_SCOPE_AGENT);
      int v3 = __hip_atomic_load(&flags[(l + 192) * 16], __ATOMIC_RELAXED, __HIP_MEMORY_SCOPE_AGENT);
      if (min(min(v0, v1), min(v2, v3)) >= phase) break;
      __builtin_amdgcn_s_sleep(2);
    }
  }
  __syncthreads();
}

// one 288-row: y = wrow . [z(32)|h(256)], optional elu, -> cstore dst
__device__ __forceinline__ void row288(const float* wr, float b,
                                       float4 z4, const float* hsrc,
                                       float* dst, bool doelu, int lane) {
  float4 w = *(const float4*)(wr + 4 * lane);
  float we = (lane < 32) ? wr[256 + lane] : 0.f;
  float4 xh = z4;
  if (lane >= 8) xh = cload4(hsrc + 4 * lane - 32);
  float s = dot4(w, xh);
  if (lane < 32) s += we * cload(hsrc + 224 + lane);
  s = wred(s);
  if (!lane) cstore(dst, doelu ? elu(s + b) : (s + b));
}

// one 256-row with cloaded activation
__device__ __forceinline__ void row256(const float* wr, float b,
                                       const float* xsrc, float* dst,
                                       bool doelu, int lane) {
  float4 w = *(const float4*)(wr + 4 * lane);
  float4 x = cload4(xsrc + 4 * lane);
  float s = wred(dot4(w, x));
  if (!lane) cstore(dst, doelu ? elu(s + b) : (s + b));
}

__global__ __launch_bounds__(BLOCK, 1) void mvae_main(P p, int* flags) {
  const int tid  = threadIdx.x;
  const int lane = tid & 63;
  const int wvin = tid >> 6;
  const int Wv   = blockIdx.x * 4 + wvin;    // 0..1023

  __shared__ float s_o[384];
  __shared__ float s_gg[8];

  // ===== S0: enc0 (rows 0..255 -> waves 0..255) =====
  if (Wv < 256) {
    const float* wr = p.ew0 + Wv * 124;
    float wa = wr[lane];
    float wb = (lane < 60) ? wr[64 + lane] : 0.f;
    float xa = (lane < 62) ? p.prev[lane] : p.curr[lane - 62];
    float xb = (lane < 60) ? p.curr[lane + 2] : 0.f;
    float s = wred(wa * xa + wb * xb);
    if (!lane) cstore(&g_a0[Wv], elu(s + p.eb0[Wv]));
  }
  gridbar(flags, 1);

  // ===== S1: enc1 =====
  if (Wv < 256)
    row256(p.ew1 + Wv * 256, p.eb1[Wv], g_a0, &g_a1[Wv], true, lane);
  gridbar(flags, 2);

  // ===== S2: enc2 =====
  if (Wv < 256)
    row256(p.ew2 + Wv * 256, p.eb2[Wv], g_a1, &g_a2[Wv], true, lane);
  gridbar(flags, 3);

  // ===== S3: mu / logvar (rows 0..63 -> waves 0..63) =====
  if (Wv < 64) {
    const float* wr = (Wv < 32) ? p.muw + Wv * 256 : p.lvw + (Wv - 32) * 256;
    float4 w = *(const float4*)(wr + 4 * lane);
    float4 x = cload4(g_a2 + 4 * lane);
    float s = wred(dot4(w, x));
    if (!lane) {
      if (Wv < 32) { float v = s + p.mub[Wv]; cstore(&g_mu[Wv], v); p.out[62 + Wv] = v; }
      else { int r = Wv - 32; float v = s + p.lvb[r]; cstore(&g_lv[r], v); p.out[94 + r] = v; }
    }
  }
  gridbar(flags, 4);

  // ===== z per wave (sc1 loads of mu/lv; z4 built via shuffles) =====
  float zs = 0.f;
  if (lane < 32)
    zs = cload(&g_mu[lane]) + p.eps[lane] * expf(0.5f * cload(&g_lv[lane]));
  float4 z4;
  z4.x = __shfl(zs, (4 * lane + 0) & 63, 64);
  z4.y = __shfl(zs, (4 * lane + 1) & 63, 64);
  z4.z = __shfl(zs, (4 * lane + 2) & 63, 64);
  z4.w = __shfl(zs, (4 * lane + 3) & 63, 64);
  float prevA = (lane >= 32 && lane < 94) ? p.prev[lane - 32] : 0.f;
  float prevB = (lane < 30) ? p.prev[32 + lane] : 0.f;
  float xa94 = (lane < 32) ? zs : prevA;

  // ===== S4: gate0 + expert h0 (1792 rows of len 94; 2 rows/wave) =====
  {
#pragma unroll
    for (int k = 0; k < 2; ++k) {
      int r = Wv + 1024 * k;
      if (r < 1792) {
        const float* wr = (r < 256) ? p.gw0 + r * 94 : p.xw0 + (size_t)(r - 256) * 94;
        float wa = wr[lane];
        float wb = (lane < 30) ? wr[64 + lane] : 0.f;
        float s = wred(wa * xa94 + wb * prevB);
        if (!lane) {
          if (r < 256) cstore(&g_g0[r], elu(s + p.gb0[r]));
          else         cstore(&g_h0[r - 256], elu(s + p.xb0[r - 256]));
        }
      }
    }
  }
  gridbar(flags, 5);

  // ===== S5: gate1 + expert h1 =====
  {
#pragma unroll
    for (int k = 0; k < 2; ++k) {
      int r = Wv + 1024 * k;
      if (r < 1792) {
        if (r < 256)
          row256(p.gw1 + r * 256, p.gb1[r], g_g0, &g_g1[r], true, lane);
        else {
          int q = r - 256, e = q >> 8;
          row288(p.xw1 + (size_t)q * 288, p.xb1[q], z4, g_h0 + e * 256,
                 &g_h1[q], true, lane);
        }
      }
    }
  }
  gridbar(flags, 6);

  // ===== S6: gate2 + expert h2 =====
  {
#pragma unroll
    for (int k = 0; k < 2; ++k) {
      int r = Wv + 1024 * k;
      if (r < 1792) {
        if (r < 256)
          row256(p.gw2 + r * 256, p.gb2[r], g_g1, &g_g2[r], true, lane);
        else {
          int q = r - 256, e = q >> 8;
          row288(p.xw2 + (size_t)q * 288, p.xb2[q], z4, g_h1 + e * 256,
                 &g_h2[q], true, lane);
        }
      }
    }
  }
  gridbar(flags, 7);

  // ===== S7: gate3 logits (6) + out_e (372) -> waves 0..377 =====
  if (Wv < 6) {
    row256(p.gw3 + Wv * 256, p.gb3[Wv], g_g2, &g_gates[Wv], false, lane);
  } else if (Wv < 378) {
    int q = Wv - 6, e = q / 62;
    row288(p.xw3 + (size_t)q * 288, p.xb3[q], z4, g_h2 + e * 256,
           &g_oute[q], false, lane);
  }
  gridbar(flags, 8);

  // ===== S8: decode (WG 0) =====
  if (blockIdx.x == 0) {
    s_o[tid] = cload(&g_oute[tid]);
    if (tid < 116) s_o[tid + 256] = cload(&g_oute[tid + 256]);
    if (tid < 6)   s_gg[tid] = cload(&g_gates[tid]);
    __syncthreads();
    if (tid < 62) {
      float s = 0.f;
#pragma unroll
      for (int e = 0; e < 6; ++e) s += s_o[e * 62 + tid] * s_gg[e];
      p.out[tid] = s;
    }
  }
}

extern "C" void kernel_launch(void* const* d_in, const int* in_sizes, int n_in,
                              void* d_out, int out_size, void* d_ws, size_t ws_size,
                              hipStream_t stream) {
  (void)in_sizes; (void)n_in; (void)out_size; (void)ws_size;
  const float* const* in = (const float* const*)d_in;
  P p;
  p.prev = in[0];  p.curr = in[1];  p.eps = in[2];
  p.ew0 = in[3];   p.eb0 = in[4];   p.ew1 = in[5];  p.eb1 = in[6];
  p.ew2 = in[7];   p.eb2 = in[8];
  p.muw = in[9];   p.mub = in[10];  p.lvw = in[11]; p.lvb = in[12];
  p.gw0 = in[13];  p.gb0 = in[14];  p.gw1 = in[15]; p.gb1 = in[16];
  p.gw2 = in[17];  p.gb2 = in[18];  p.gw3 = in[19]; p.gb3 = in[20];
  p.xw0 = in[21];  p.xb0 = in[22];  p.xw1 = in[23]; p.xb1 = in[24];
  p.xw2 = in[25];  p.xb2 = in[26];  p.xw3 = in[27]; p.xb3 = in[28];
  p.out = (float*)d_out;

  int* flags = (int*)d_ws;                 // 256 WGs x 1 cacheline
  hipMemsetAsync(flags, 0, NWG * 16 * sizeof(int), stream);
  mvae_main<<<NWG, BLOCK, 0, stream>>>(p, flags);
}

// Round 14
// 32.490 us; speedup vs baseline: 5.7160x; 1.0857x over previous
//
#include <hip/hip_runtime.h>
#include <math.h>

// MVAE forward, round 14 = round 13 (PASSED, 35.3us) + two overhead cuts:
// 1) NO memset node: phase-indexed flag slots; arrive stores MAGIC, poll
//    checks ==MAGIC (garbage/poison-safe); WG0 zeroes all slots after the
//    final barrier (safe: its bar8-poll passing proves all WGs passed all
//    earlier polls and never poll again this call). Zero extra dispatches.
// 2) Entry gll16 weight staging (r5-proven row patterns, un-sinkable):
//    per-wave rows (~9.6KB/wave) stream into LDS during S0..S3 barrier
//    dead-time; S4..S7 then pay only the activation-cload round trip.
// Stage structure, distribution, cstore/cload discipline: r13 verbatim.

#define NWG   256
#define BLOCK 256
#define MAGIC 0x7E57A11E

__device__ __align__(128) float g_a0[256];
__device__ __align__(128) float g_a1[256];
__device__ __align__(128) float g_a2[256];
__device__ __align__(128) float g_mu[32];
__device__ __align__(128) float g_lv[32];
__device__ __align__(128) float g_g0[256];
__device__ __align__(128) float g_g1[256];
__device__ __align__(128) float g_g2[256];
__device__ __align__(128) float g_gates[32];
__device__ __align__(128) float g_h0[1536];
__device__ __align__(128) float g_h1[1536];
__device__ __align__(128) float g_h2[1536];
__device__ __align__(128) float g_oute[384];

struct P {
  const float *prev, *curr, *eps;
  const float *ew0,*eb0,*ew1,*eb1,*ew2,*eb2;
  const float *muw,*mub,*lvw,*lvb;
  const float *gw0,*gb0,*gw1,*gb1,*gw2,*gb2,*gw3,*gb3;
  const float *xw0,*xb0,*xw1,*xb1,*xw2,*xb2,*xw3,*xb3;
  float* out;
};

__device__ __forceinline__ float cload(const float* a) {
  int v = __hip_atomic_load((const int*)a, __ATOMIC_RELAXED,
                            __HIP_MEMORY_SCOPE_AGENT);
  return __int_as_float(v);
}
__device__ __forceinline__ void cstore(float* a, float v) {
  __hip_atomic_store((int*)a, __float_as_int(v), __ATOMIC_RELAXED,
                     __HIP_MEMORY_SCOPE_AGENT);
}
__device__ __forceinline__ float4 cload4(const float* a) {
  float4 r;
  r.x = cload(a + 0); r.y = cload(a + 1);
  r.z = cload(a + 2); r.w = cload(a + 3);
  return r;
}
__device__ __forceinline__ void gll16(const void* g, void* l) {
  __builtin_amdgcn_global_load_lds((const __attribute__((address_space(1))) void*)g,
                                   (__attribute__((address_space(3))) void*)l,
                                   16, 0, 0);
}
__device__ __forceinline__ void gll4(const void* g, void* l) {
  __builtin_amdgcn_global_load_lds((const __attribute__((address_space(1))) void*)g,
                                   (__attribute__((address_space(3))) void*)l,
                                   4, 0, 0);
}
__device__ __forceinline__ float wred(float v) {
#pragma unroll
  for (int m = 32; m; m >>= 1) v += __shfl_xor(v, m, 64);
  return v;
}
__device__ __forceinline__ float elu(float x) { return x > 0.f ? x : expm1f(x); }
__device__ __forceinline__ float dot4(float4 a, float4 b) {
  return a.x*b.x + a.y*b.y + a.z*b.z + a.w*b.w;
}

// ---- phase-slot flags: slot(ph, wg) at flags[((ph-1)*NWG + wg)*16] ----
__device__ __forceinline__ int* slotp(int* flags, int ph, int wg) {
  return &flags[((ph - 1) * NWG + wg) * 16];
}
__device__ __forceinline__ void bar_arrive(int* flags, int ph) {
  __syncthreads();                 // vmcnt(0) drain: sc1 stores ack'd at MALL
  if (threadIdx.x == 0)
    __hip_atomic_store(slotp(flags, ph, blockIdx.x), MAGIC,
                       __ATOMIC_RELAXED, __HIP_MEMORY_SCOPE_AGENT);
}
__device__ __forceinline__ void bar_poll(int* flags, int ph) {
  if (threadIdx.x < 64) {
    const int l = threadIdx.x;
    for (;;) {
      int v0 = __hip_atomic_load(slotp(flags, ph, l),       __ATOMIC_RELAXED, __HIP_MEMORY_SCOPE_AGENT);
      int v1 = __hip_atomic_load(slotp(flags, ph, l +  64), __ATOMIC_RELAXED, __HIP_MEMORY_SCOPE_AGENT);
      int v2 = __hip_atomic_load(slotp(flags, ph, l + 128), __ATOMIC_RELAXED, __HIP_MEMORY_SCOPE_AGENT);
      int v3 = __hip_atomic_load(slotp(flags, ph, l + 192), __ATOMIC_RELAXED, __HIP_MEMORY_SCOPE_AGENT);
      if (v0 == MAGIC && v1 == MAGIC && v2 == MAGIC && v3 == MAGIC) break;
      __builtin_amdgcn_s_sleep(2);
    }
  }
  __syncthreads();
}
__device__ __forceinline__ void gridbar(int* flags, int ph) {
  bar_arrive(flags, ph);
  bar_poll(flags, ph);
}

__global__ __launch_bounds__(BLOCK, 1) void mvae_main(P p, int* flags) {
  const int tid  = threadIdx.x;
  const int lane = tid & 63;
  const int wvin = tid >> 6;
  const int Wv   = blockIdx.x * 4 + wvin;    // 0..1023

  __shared__ __align__(16) float s_w1[4][256];
  __shared__ __align__(16) float s_w2[4][256];
  __shared__ __align__(16) float s_w3[4][256];
  __shared__ __align__(16) float s_w4[4][2][96];
  __shared__ __align__(16) float s_w5[4][2][288];
  __shared__ __align__(16) float s_w6[4][2][288];
  __shared__ __align__(16) float s_w7[4][288];
  __shared__ float s_o[384];
  __shared__ float s_gg[8];

  // ================= ENTRY STAGING: per-wave weight rows -> LDS ===========
  if (Wv < 256) {
    gll16(p.ew1 + Wv * 256 + lane * 4, s_w1[wvin]);
    gll16(p.ew2 + Wv * 256 + lane * 4, s_w2[wvin]);
  }
  if (Wv < 64) {
    const float* src = (Wv < 32) ? p.muw + Wv * 256 : p.lvw + (Wv - 32) * 256;
    gll16(src + lane * 4, s_w3[wvin]);
  }
#pragma unroll
  for (int k = 0; k < 2; ++k) {            // S4: rows Wv+1024k, 94 floats
    int r = Wv + 1024 * k;
    if (r < 1792) {
      const float* src = (r < 256) ? p.gw0 + r * 94 : p.xw0 + (size_t)(r - 256) * 94;
      float* dst = s_w4[wvin][k];
      if (lane < 23)       gll16(src + lane * 4, dst);
      else if (lane == 23) { gll4(src + 92, dst + 69);    // -> float 92
                             gll4(src + 93, dst + 70); }  // -> float 93
    }
  }
#pragma unroll
  for (int k = 0; k < 2; ++k) {            // S5
    int r = Wv + 1024 * k;
    if (r < 1792) {
      float* dst = s_w5[wvin][k];
      if (r < 256) gll16(p.gw1 + r * 256 + lane * 4, dst);
      else {
        const float* src = p.xw1 + (size_t)(r - 256) * 288;
        gll16(src + lane * 4, dst);
        if (lane < 8) gll16(src + 256 + lane * 4, dst + 256);
      }
    }
  }
#pragma unroll
  for (int k = 0; k < 2; ++k) {            // S6
    int r = Wv + 1024 * k;
    if (r < 1792) {
      float* dst = s_w6[wvin][k];
      if (r < 256) gll16(p.gw2 + r * 256 + lane * 4, dst);
      else {
        const float* src = p.xw2 + (size_t)(r - 256) * 288;
        gll16(src + lane * 4, dst);
        if (lane < 8) gll16(src + 256 + lane * 4, dst + 256);
      }
    }
  }
  if (Wv < 6) {                            // S7
    gll16(p.gw3 + Wv * 256 + lane * 4, s_w7[wvin]);
  } else if (Wv < 378) {
    const float* src = p.xw3 + (size_t)(Wv - 6) * 288;
    float* dst = s_w7[wvin];
    gll16(src + lane * 4, dst);
    if (lane < 8) gll16(src + 256 + lane * 4, dst + 256);
  }

  // ===== S0: enc0 (plain loads; staging streams concurrently) =====
  if (Wv < 256) {
    const float* wr = p.ew0 + Wv * 124;
    float wa = wr[lane];
    float wb = (lane < 60) ? wr[64 + lane] : 0.f;
    float xa = (lane < 62) ? p.prev[lane] : p.curr[lane - 62];
    float xb = (lane < 60) ? p.curr[lane + 2] : 0.f;
    float s = wred(wa * xa + wb * xb);
    if (!lane) cstore(&g_a0[Wv], elu(s + p.eb0[Wv]));
  }
  gridbar(flags, 1);   // arrive's syncthreads drains staging too

  // ===== S1: enc1 (weights from LDS) =====
  if (Wv < 256) {
    float4 w = *(const float4*)(s_w1[wvin] + 4 * lane);
    float4 x = cload4(g_a0 + 4 * lane);
    float s = wred(dot4(w, x));
    if (!lane) cstore(&g_a1[Wv], elu(s + p.eb1[Wv]));
  }
  gridbar(flags, 2);

  // ===== S2: enc2 =====
  if (Wv < 256) {
    float4 w = *(const float4*)(s_w2[wvin] + 4 * lane);
    float4 x = cload4(g_a1 + 4 * lane);
    float s = wred(dot4(w, x));
    if (!lane) cstore(&g_a2[Wv], elu(s + p.eb2[Wv]));
  }
  gridbar(flags, 3);

  // ===== S3: mu / logvar (waves 0..63) =====
  if (Wv < 64) {
    float4 w = *(const float4*)(s_w3[wvin] + 4 * lane);
    float4 x = cload4(g_a2 + 4 * lane);
    float s = wred(dot4(w, x));
    if (!lane) {
      if (Wv < 32) { float v = s + p.mub[Wv]; cstore(&g_mu[Wv], v); p.out[62 + Wv] = v; }
      else { int r = Wv - 32; float v = s + p.lvb[r]; cstore(&g_lv[r], v); p.out[94 + r] = v; }
    }
  }
  gridbar(flags, 4);

  // ===== z per wave (sc1 mu/lv; z4 via shuffles) =====
  float zs = 0.f;
  if (lane < 32)
    zs = cload(&g_mu[lane]) + p.eps[lane] * expf(0.5f * cload(&g_lv[lane]));
  float4 z4;
  z4.x = __shfl(zs, (4 * lane + 0) & 63, 64);
  z4.y = __shfl(zs, (4 * lane + 1) & 63, 64);
  z4.z = __shfl(zs, (4 * lane + 2) & 63, 64);
  z4.w = __shfl(zs, (4 * lane + 3) & 63, 64);
  float prevA = (lane >= 32 && lane < 94) ? p.prev[lane - 32] : 0.f;
  float prevB = (lane < 30) ? p.prev[32 + lane] : 0.f;
  float xa94 = (lane < 32) ? zs : prevA;

  // ===== S4: gate0 + expert h0 (rows of len 94; 2/wave, LDS weights) =====
#pragma unroll
  for (int k = 0; k < 2; ++k) {
    int r = Wv + 1024 * k;
    if (r < 1792) {
      const float* wrow = s_w4[wvin][k];
      float wa = wrow[lane];
      float wb = (lane < 30) ? wrow[64 + lane] : 0.f;
      float s = wred(wa * xa94 + wb * prevB);
      if (!lane) {
        if (r < 256) cstore(&g_g0[r], elu(s + p.gb0[r]));
        else         cstore(&g_h0[r - 256], elu(s + p.xb0[r - 256]));
      }
    }
  }
  gridbar(flags, 5);

  // ===== S5: gate1 + expert h1 =====
#pragma unroll
  for (int k = 0; k < 2; ++k) {
    int r = Wv + 1024 * k;
    if (r < 1792) {
      const float* wrow = s_w5[wvin][k];
      float4 w = *(const float4*)(wrow + 4 * lane);
      if (r < 256) {
        float4 x = cload4(g_g0 + 4 * lane);
        float s = wred(dot4(w, x));
        if (!lane) cstore(&g_g1[r], elu(s + p.gb1[r]));
      } else {
        int q = r - 256, e = q >> 8;
        const float* hsrc = g_h0 + e * 256;
        float4 xh = z4;
        if (lane >= 8) xh = cload4(hsrc + 4 * lane - 32);
        float s = dot4(w, xh);
        if (lane < 32) s += wrow[256 + lane] * cload(hsrc + 224 + lane);
        s = wred(s);
        if (!lane) cstore(&g_h1[q], elu(s + p.xb1[q]));
      }
    }
  }
  gridbar(flags, 6);

  // ===== S6: gate2 + expert h2 =====
#pragma unroll
  for (int k = 0; k < 2; ++k) {
    int r = Wv + 1024 * k;
    if (r < 1792) {
      const float* wrow = s_w6[wvin][k];
      float4 w = *(const float4*)(wrow + 4 * lane);
      if (r < 256) {
        float4 x = cload4(g_g1 + 4 * lane);
        float s = wred(dot4(w, x));
        if (!lane) cstore(&g_g2[r], elu(s + p.gb2[r]));
      } else {
        int q = r - 256, e = q >> 8;
        const float* hsrc = g_h1 + e * 256;
        float4 xh = z4;
        if (lane >= 8) xh = cload4(hsrc + 4 * lane - 32);
        float s = dot4(w, xh);
        if (lane < 32) s += wrow[256 + lane] * cload(hsrc + 224 + lane);
        s = wred(s);
        if (!lane) cstore(&g_h2[q], elu(s + p.xb2[q]));
      }
    }
  }
  gridbar(flags, 7);

  // ===== S7: gate3 logits (6) + out_e (372) =====
  if (Wv < 6) {
    float4 w = *(const float4*)(s_w7[wvin] + 4 * lane);
    float4 x = cload4(g_g2 + 4 * lane);
    float s = wred(dot4(w, x));
    if (!lane) cstore(&g_gates[Wv], s + p.gb3[Wv]);    // raw logits
  } else if (Wv < 378) {
    int q = Wv - 6, e = q / 62;
    const float* wrow = s_w7[wvin];
    float4 w = *(const float4*)(wrow + 4 * lane);
    const float* hsrc = g_h2 + e * 256;
    float4 xh = z4;
    if (lane >= 8) xh = cload4(hsrc + 4 * lane - 32);
    float s = dot4(w, xh);
    if (lane < 32) s += wrow[256 + lane] * cload(hsrc + 224 + lane);
    s = wred(s);
    if (!lane) cstore(&g_oute[q], s + p.xb3[q]);
  }

  // ===== bar8: all arrive; only WG0 polls (decode) =====
  bar_arrive(flags, 8);
  if (blockIdx.x != 0) return;
  bar_poll(flags, 8);

  // ===== S8: decode (WG0) =====
  s_o[tid] = cload(&g_oute[tid]);
  if (tid < 116) s_o[tid + 256] = cload(&g_oute[tid + 256]);
  if (tid < 6)   s_gg[tid] = cload(&g_gates[tid]);
  __syncthreads();
  if (tid < 62) {
    float s = 0.f;
#pragma unroll
    for (int e = 0; e < 6; ++e) s += s_o[e * 62 + tid] * s_gg[e];
    p.out[tid] = s;
  }

  // ===== cleanup: zero all flag slots for the next call =====
  // Safe: WG0 passed bar8's poll => every WG arrived bar8 => every WG passed
  // all earlier polls and never polls again this call.
#pragma unroll
  for (int ph = 1; ph <= 8; ++ph)
    __hip_atomic_store(slotp(flags, ph, tid), 0,
                       __ATOMIC_RELAXED, __HIP_MEMORY_SCOPE_AGENT);
}

extern "C" void kernel_launch(void* const* d_in, const int* in_sizes, int n_in,
                              void* d_out, int out_size, void* d_ws, size_t ws_size,
                              hipStream_t stream) {
  (void)in_sizes; (void)n_in; (void)out_size; (void)ws_size;
  const float* const* in = (const float* const*)d_in;
  P p;
  p.prev = in[0];  p.curr = in[1];  p.eps = in[2];
  p.ew0 = in[3];   p.eb0 = in[4];   p.ew1 = in[5];  p.eb1 = in[6];
  p.ew2 = in[7];   p.eb2 = in[8];
  p.muw = in[9];   p.mub = in[10];  p.lvw = in[11]; p.lvb = in[12];
  p.gw0 = in[13];  p.gb0 = in[14];  p.gw1 = in[15]; p.gb1 = in[16];
  p.gw2 = in[17];  p.gb2 = in[18];  p.gw3 = in[19]; p.gb3 = in[20];
  p.xw0 = in[21];  p.xb0 = in[22];  p.xw1 = in[23]; p.xb1 = in[24];
  p.xw2 = in[25];  p.xb2 = in[26];  p.xw3 = in[27]; p.xb3 = in[28];
  p.out = (float*)d_out;

  int* flags = (int*)d_ws;     // 8 phases x 256 WGs x 64B = 128KB, self-cleaning
  mvae_main<<<NWG, BLOCK, 0, stream>>>(p, flags);
}